// Round 4
// baseline (1182.224 us; speedup 1.0000x reference)
//
#include <hip/hip_runtime.h>
#include <hip/hip_cooperative_groups.h>

namespace cg = cooperative_groups;

// N=10000, E=50000, IN=32, H=64 (derived from in_sizes at launch).
//
// theta[e] = sum_k ea[e,k]*W_k + B  =>  msg[e] = sum_k ea[e,k]*(h@W_k)[src] + (h@B)[src]
// Per iter: ZZ[N,576] = h @ [W0|W1|W2|W3|B|root_w|w_hh^T]; CSR gather-agg;
//           m = relu(agg + root + conv_b); gi = m@w_ih^T; GRU elementwise.
// All phases fused in ONE cooperative kernel with grid syncs (launch overhead killer).

#define AP 65  // (65j+r)%32 == (j+r)%32 -> conflict-free transposed staging writes
#define WP 68  // float4-aligned rows for w tiles

__device__ __forceinline__ float sigmoidf_(float x) { return 1.0f / (1.0f + __expf(-x)); }
__device__ __forceinline__ float tanhf_(float x) { return 2.0f / (1.0f + __expf(-2.0f * x)) - 1.0f; }

struct Args {
    const float* x; const int* ei; const float* ea;
    const float* lin0_w; const float* lin0_b;
    const float* nn_w; const float* nn_b; const float* root_w; const float* conv_b;
    const float* w_ih; const float* w_hh; const float* b_ih; const float* b_hh;
    float* ZZ; float* h; float* m; float* eattr;
    int* rowptr; int* cursor; int* esrc; int* dcnt; int* bsum; int* boff;
    float* out; int N; int E; int RB;
};

__global__ __launch_bounds__(256, 4) void fused(Args p) {
    cg::grid_group grid = cg::this_grid();
    __shared__ float a_lds[64 * AP];
    __shared__ float w_lds[64 * WP];
    __shared__ int ibuf[256];
    const int tid = threadIdx.x, bid = blockIdx.x, nb = gridDim.x;
    const int gid = bid * 256 + tid, gsz = nb * 256;
    const int N = p.N, E = p.E, RB = p.RB;

    // ---- P0: lin0 (h = relu(x@lin0_w+b)) + zero dcnt ----
    for (int i = gid; i < N; i += gsz) p.dcnt[i] = 0;
    for (int idx = gid; idx < N * 64; idx += gsz) {
        int n = idx >> 6, l = idx & 63;
        float acc = p.lin0_b[l];
#pragma unroll
        for (int j = 0; j < 32; ++j) acc = fmaf(p.x[n * 32 + j], p.lin0_w[j * 64 + l], acc);
        p.h[idx] = fmaxf(acc, 0.0f);
    }
    grid.sync();

    // ---- P1: degree count ----
    for (int e = gid; e < E; e += gsz) atomicAdd(p.dcnt + p.ei[E + e], 1);
    grid.sync();

    // ---- P2: per-block partial sums of dcnt ----
    const int chunk = (N + nb - 1) / nb;
    {
        int c0 = bid * chunk, c1 = min(c0 + chunk, N);
        int local = 0;
        for (int i = c0 + tid; i < c1; i += 256) local += p.dcnt[i];
        ibuf[tid] = local;
        __syncthreads();
        for (int d = 128; d > 0; d >>= 1) {
            if (tid < d) ibuf[tid] += ibuf[tid + d];
            __syncthreads();
        }
        if (tid == 0) p.bsum[bid] = ibuf[0];
    }
    grid.sync();

    // ---- P3: block 0 exclusive-scans bsum[nb] (nb <= 2048) ----
    if (bid == 0) {
        int base = tid * 8;
        int loc[8];
        int running = 0;
#pragma unroll
        for (int k = 0; k < 8; ++k) {
            int i = base + k;
            int v = (i < nb) ? p.bsum[i] : 0;
            loc[k] = running;
            running += v;
        }
        ibuf[tid] = running;
        __syncthreads();
        for (int d = 1; d < 256; d <<= 1) {
            int u = (tid >= d) ? ibuf[tid - d] : 0;
            __syncthreads();
            ibuf[tid] += u;
            __syncthreads();
        }
        int off = ibuf[tid] - running;
#pragma unroll
        for (int k = 0; k < 8; ++k) {
            int i = base + k;
            if (i < nb) p.boff[i] = off + loc[k];
        }
    }
    grid.sync();

    // ---- P4: rowptr/cursor fill (serial over tiny chunk) ----
    if (tid == 0) {
        int c0 = bid * chunk, c1 = min(c0 + chunk, N);
        int run = p.boff[bid];
        for (int i = c0; i < c1; ++i) {
            p.rowptr[i] = run;
            p.cursor[i] = run;
            run += p.dcnt[i];
        }
        if (bid == 0) p.rowptr[N] = E;
    }
    grid.sync();

    // ---- P5: CSR fill ----
    for (int e = gid; e < E; e += gsz) {
        int d = p.ei[E + e];
        int pos = atomicAdd(p.cursor + d, 1);
        p.esrc[pos] = p.ei[e];
        ((float4*)p.eattr)[pos] = ((const float4*)p.ea)[e];
    }
    grid.sync();

    const int row_t = tid >> 4, col_t = tid & 15;
    const int r0 = row_t * 4, c0 = col_t * 4;
    const int lane = tid & 63;

    for (int it = 0; it < 3; ++it) {
        // ---- P6: ZZ[N,576] = h @ Wcat ----
        for (int t = bid; t < RB * 3; t += nb) {
            int rt = t % RB, g = t / RB;
            int n0 = rt * 64;
            __syncthreads();  // prev task done reading a_lds
            for (int idx = tid; idx < 4096; idx += 256) {
                int r = idx >> 6, j = idx & 63;
                int n = n0 + r;
                a_lds[j * AP + r] = (n < N) ? p.h[n * 64 + j] : 0.0f;
            }
            float acc[3][4][4] = {};
#pragma unroll
            for (int s = 0; s < 3; ++s) {
                int cb = g * 3 + s;
                __syncthreads();  // prev FMA done reading w_lds (s==0: a_lds staged)
                if (cb < 4) {
                    for (int idx = tid; idx < 4096; idx += 256) {
                        int j = idx >> 6, c = idx & 63;
                        w_lds[j * WP + c] = p.nn_w[cb * 4096 + j * 64 + c];
                    }
                } else if (cb == 4) {
                    for (int idx = tid; idx < 4096; idx += 256) {
                        int j = idx >> 6, c = idx & 63;
                        w_lds[j * WP + c] = p.nn_b[j * 64 + c];
                    }
                } else if (cb == 5) {
                    for (int idx = tid; idx < 4096; idx += 256) {
                        int j = idx >> 6, c = idx & 63;
                        w_lds[j * WP + c] = p.root_w[j * 64 + c];
                    }
                } else {
                    int g0 = (cb - 6) * 64;
                    for (int idx = tid; idx < 4096; idx += 256) {
                        int c = idx >> 6, j = idx & 63;
                        w_lds[j * WP + c] = p.w_hh[(g0 + c) * 64 + j];
                    }
                }
                __syncthreads();
#pragma unroll 4
                for (int j = 0; j < 64; ++j) {
                    float av[4];
#pragma unroll
                    for (int rr = 0; rr < 4; ++rr) av[rr] = a_lds[j * AP + r0 + rr];
                    const float4 w4 = *(const float4*)(w_lds + j * WP + c0);
                    const float wv[4] = {w4.x, w4.y, w4.z, w4.w};
#pragma unroll
                    for (int rr = 0; rr < 4; ++rr)
#pragma unroll
                        for (int cc = 0; cc < 4; ++cc)
                            acc[s][rr][cc] = fmaf(av[rr], wv[cc], acc[s][rr][cc]);
                }
            }
#pragma unroll
            for (int s = 0; s < 3; ++s) {
                int cbase = (g * 3 + s) * 64 + c0;
#pragma unroll
                for (int rr = 0; rr < 4; ++rr) {
                    int n = n0 + r0 + rr;
                    if (n < N)
                        *(float4*)(p.ZZ + (size_t)n * 576 + cbase) =
                            make_float4(acc[s][rr][0], acc[s][rr][1], acc[s][rr][2],
                                        acc[s][rr][3]);
                }
            }
        }
        grid.sync();

        // ---- P7: CSR aggregation + m = relu(agg + root + conv_b) ----
        {
            int gwave = gid >> 6;
            int wstride = gsz >> 6;
            for (int n = gwave; n < N; n += wstride) {
                int b = p.rowptr[n], e = p.rowptr[n + 1];
                float acc = 0.0f;
                int i = b;
                for (; i + 2 <= e; i += 2) {
                    int s0 = p.esrc[i], s1 = p.esrc[i + 1];
                    float4 a0 = ((const float4*)p.eattr)[i];
                    float4 a1 = ((const float4*)p.eattr)[i + 1];
                    const float* z0 = p.ZZ + (size_t)s0 * 576 + lane;
                    const float* z1 = p.ZZ + (size_t)s1 * 576 + lane;
                    float p0 = z0[0], p1 = z0[64], p2 = z0[128], p3 = z0[192], p4 = z0[256];
                    float q0 = z1[0], q1 = z1[64], q2 = z1[128], q3 = z1[192], q4 = z1[256];
                    acc += fmaf(a0.x, p0, fmaf(a0.y, p1, fmaf(a0.z, p2, fmaf(a0.w, p3, p4))));
                    acc += fmaf(a1.x, q0, fmaf(a1.y, q1, fmaf(a1.z, q2, fmaf(a1.w, q3, q4))));
                }
                if (i < e) {
                    int s0 = p.esrc[i];
                    float4 a0 = ((const float4*)p.eattr)[i];
                    const float* z0 = p.ZZ + (size_t)s0 * 576 + lane;
                    acc += fmaf(a0.x, z0[0], fmaf(a0.y, z0[64],
                                fmaf(a0.z, z0[128], fmaf(a0.w, z0[192], z0[256]))));
                }
                float v = acc + p.ZZ[(size_t)n * 576 + 320 + lane] + p.conv_b[lane];
                p.m[(size_t)n * 64 + lane] = fmaxf(v, 0.0f);
            }
        }
        grid.sync();

        // ---- P8: gi = m @ w_ih^T ; GRU elementwise ----
        for (int t = bid; t < RB; t += nb) {
            int n0 = t * 64;
            __syncthreads();
            for (int idx = tid; idx < 4096; idx += 256) {
                int r = idx >> 6, j = idx & 63;
                int n = n0 + r;
                a_lds[j * AP + r] = (n < N) ? p.m[(size_t)n * 64 + j] : 0.0f;
            }
            float acc[3][4][4] = {};
#pragma unroll
            for (int cb = 0; cb < 3; ++cb) {
                __syncthreads();
                for (int idx = tid; idx < 4096; idx += 256) {
                    int c = idx >> 6, j = idx & 63;
                    w_lds[j * WP + c] = p.w_ih[(cb * 64 + c) * 64 + j];
                }
                __syncthreads();
#pragma unroll 4
                for (int j = 0; j < 64; ++j) {
                    float av[4];
#pragma unroll
                    for (int rr = 0; rr < 4; ++rr) av[rr] = a_lds[j * AP + r0 + rr];
                    const float4 w4 = *(const float4*)(w_lds + j * WP + c0);
                    const float wv[4] = {w4.x, w4.y, w4.z, w4.w};
#pragma unroll
                    for (int rr = 0; rr < 4; ++rr)
#pragma unroll
                        for (int cc = 0; cc < 4; ++cc)
                            acc[cb][rr][cc] = fmaf(av[rr], wv[cc], acc[cb][rr][cc]);
                }
            }
            float* of = (it == 2) ? p.out : nullptr;
#pragma unroll
            for (int rr = 0; rr < 4; ++rr) {
                int n = n0 + r0 + rr;
                if (n >= N) continue;
                const float4 ghr4 = *(const float4*)(p.ZZ + (size_t)n * 576 + 384 + c0);
                const float4 ghz4 = *(const float4*)(p.ZZ + (size_t)n * 576 + 448 + c0);
                const float4 ghn4 = *(const float4*)(p.ZZ + (size_t)n * 576 + 512 + c0);
                const float4 hv4 = *(const float4*)(p.h + (size_t)n * 64 + c0);
                const float ghr[4] = {ghr4.x, ghr4.y, ghr4.z, ghr4.w};
                const float ghz[4] = {ghz4.x, ghz4.y, ghz4.z, ghz4.w};
                const float ghn[4] = {ghn4.x, ghn4.y, ghn4.z, ghn4.w};
                const float hv[4] = {hv4.x, hv4.y, hv4.z, hv4.w};
                float hnew[4];
#pragma unroll
                for (int cc = 0; cc < 4; ++cc) {
                    int l = c0 + cc;
                    float rg = sigmoidf_(acc[0][rr][cc] + p.b_ih[l] + ghr[cc] + p.b_hh[l]);
                    float zg = sigmoidf_(acc[1][rr][cc] + p.b_ih[64 + l] + ghz[cc] + p.b_hh[64 + l]);
                    float hn = ghn[cc] + p.b_hh[128 + l];
                    float ng = tanhf_(acc[2][rr][cc] + p.b_ih[128 + l] + rg * hn);
                    hnew[cc] = (1.0f - zg) * ng + zg * hv[cc];
                }
                float4 o = make_float4(hnew[0], hnew[1], hnew[2], hnew[3]);
                *(float4*)(p.h + (size_t)n * 64 + c0) = o;
                if (of) *(float4*)(of + (size_t)n * 64 + c0) = o;
            }
        }
        grid.sync();
    }
}

// ======================= fallback path (round-3, known-good) ========================
__global__ __launch_bounds__(256) void lin0_k(const float* __restrict__ x,
                                              const float* __restrict__ w,
                                              const float* __restrict__ b,
                                              float* __restrict__ h, int N) {
    int gid = blockIdx.x * 256 + threadIdx.x;
    int n = gid >> 6, l = gid & 63;
    if (n >= N) return;
    float acc = b[l];
#pragma unroll
    for (int j = 0; j < 32; ++j) acc = fmaf(x[n * 32 + j], w[j * 64 + l], acc);
    h[n * 64 + l] = fmaxf(acc, 0.0f);
}

__global__ __launch_bounds__(256) void count_k(const int* __restrict__ ei,
                                               int* __restrict__ dcnt, int E) {
    int e = blockIdx.x * 256 + threadIdx.x;
    if (e < E) atomicAdd(dcnt + ei[E + e], 1);
}
__global__ __launch_bounds__(256) void zero_k(int* __restrict__ a, int n) {
    int i = blockIdx.x * 256 + threadIdx.x;
    if (i < n) a[i] = 0;
}

__global__ __launch_bounds__(1024) void scan_k(const int* __restrict__ dcnt,
                                               int* __restrict__ rowptr,
                                               int* __restrict__ cursor, int N) {
    __shared__ int part[1024];
    const int t = threadIdx.x;
    const int per = (N + 1023) >> 10;
    const int s0 = t * per;
    const int e0 = min(s0 + per, N);
    int sum = 0;
    for (int i = s0; i < e0; ++i) sum += dcnt[i];
    part[t] = sum;
    __syncthreads();
    for (int d = 1; d < 1024; d <<= 1) {
        int u = (t >= d) ? part[t - d] : 0;
        __syncthreads();
        part[t] += u;
        __syncthreads();
    }
    int off = part[t] - sum;
    for (int i = s0; i < e0; ++i) {
        rowptr[i] = off;
        cursor[i] = off;
        off += dcnt[i];
    }
    if (e0 == N && s0 < N) rowptr[N] = off;
}

__global__ __launch_bounds__(256) void fill_k(const int* __restrict__ ei,
                                              const float4* __restrict__ ea,
                                              int* __restrict__ cursor,
                                              int* __restrict__ esrc,
                                              float4* __restrict__ eattr, int E) {
    int e = blockIdx.x * 256 + threadIdx.x;
    if (e >= E) return;
    int d = ei[E + e];
    int pos = atomicAdd(cursor + d, 1);
    esrc[pos] = ei[e];
    eattr[pos] = ea[e];
}

__global__ __launch_bounds__(256) void gemm_a3(const float* __restrict__ h,
                                               const float* __restrict__ nn_w,
                                               const float* __restrict__ nn_b,
                                               const float* __restrict__ root_w,
                                               const float* __restrict__ w_hh,
                                               float* __restrict__ ZZ, int N) {
    __shared__ float a_lds[64 * AP];
    __shared__ float w_lds[64 * WP];
    const int n0 = blockIdx.x * 64;
    const int g = blockIdx.y;
    const int tid = threadIdx.x;
    for (int idx = tid; idx < 4096; idx += 256) {
        int r = idx >> 6, j = idx & 63;
        int n = n0 + r;
        a_lds[j * AP + r] = (n < N) ? h[n * 64 + j] : 0.0f;
    }
    const int row_t = tid >> 4, col_t = tid & 15;
    const int r0 = row_t * 4, c0 = col_t * 4;
    float acc[3][4][4] = {};
#pragma unroll
    for (int s = 0; s < 3; ++s) {
        int cb = g * 3 + s;
        __syncthreads();
        if (cb < 4) {
            for (int idx = tid; idx < 4096; idx += 256) {
                int j = idx >> 6, c = idx & 63;
                w_lds[j * WP + c] = nn_w[cb * 4096 + j * 64 + c];
            }
        } else if (cb == 4) {
            for (int idx = tid; idx < 4096; idx += 256) {
                int j = idx >> 6, c = idx & 63;
                w_lds[j * WP + c] = nn_b[j * 64 + c];
            }
        } else if (cb == 5) {
            for (int idx = tid; idx < 4096; idx += 256) {
                int j = idx >> 6, c = idx & 63;
                w_lds[j * WP + c] = root_w[j * 64 + c];
            }
        } else {
            int g0 = (cb - 6) * 64;
            for (int idx = tid; idx < 4096; idx += 256) {
                int c = idx >> 6, j = idx & 63;
                w_lds[j * WP + c] = w_hh[(g0 + c) * 64 + j];
            }
        }
        __syncthreads();
#pragma unroll 4
        for (int j = 0; j < 64; ++j) {
            float av[4];
#pragma unroll
            for (int rr = 0; rr < 4; ++rr) av[rr] = a_lds[j * AP + r0 + rr];
            const float4 w4 = *(const float4*)(w_lds + j * WP + c0);
            const float wv[4] = {w4.x, w4.y, w4.z, w4.w};
#pragma unroll
            for (int rr = 0; rr < 4; ++rr)
#pragma unroll
                for (int cc = 0; cc < 4; ++cc)
                    acc[s][rr][cc] = fmaf(av[rr], wv[cc], acc[s][rr][cc]);
        }
    }
#pragma unroll
    for (int s = 0; s < 3; ++s) {
        const int cbase = (g * 3 + s) * 64 + c0;
#pragma unroll
        for (int rr = 0; rr < 4; ++rr) {
            int n = n0 + r0 + rr;
            if (n < N)
                *(float4*)(ZZ + (size_t)n * 576 + cbase) =
                    make_float4(acc[s][rr][0], acc[s][rr][1], acc[s][rr][2], acc[s][rr][3]);
        }
    }
}

__global__ __launch_bounds__(256) void agg_k(const int* __restrict__ rowptr,
                                             const int* __restrict__ esrc,
                                             const float4* __restrict__ eattr,
                                             const float* __restrict__ ZZ,
                                             const float* __restrict__ conv_b,
                                             float* __restrict__ m, int N) {
    int n = blockIdx.x * 4 + (threadIdx.x >> 6);
    int lane = threadIdx.x & 63;
    if (n >= N) return;
    const int b = rowptr[n], e = rowptr[n + 1];
    float acc = 0.0f;
    int i = b;
    for (; i + 2 <= e; i += 2) {
        int s0 = esrc[i], s1 = esrc[i + 1];
        float4 a0 = eattr[i], a1 = eattr[i + 1];
        const float* z0 = ZZ + (size_t)s0 * 576 + lane;
        const float* z1 = ZZ + (size_t)s1 * 576 + lane;
        float p0 = z0[0], p1 = z0[64], p2 = z0[128], p3 = z0[192], p4 = z0[256];
        float q0 = z1[0], q1 = z1[64], q2 = z1[128], q3 = z1[192], q4 = z1[256];
        acc += fmaf(a0.x, p0, fmaf(a0.y, p1, fmaf(a0.z, p2, fmaf(a0.w, p3, p4))));
        acc += fmaf(a1.x, q0, fmaf(a1.y, q1, fmaf(a1.z, q2, fmaf(a1.w, q3, q4))));
    }
    if (i < e) {
        int s0 = esrc[i];
        float4 a0 = eattr[i];
        const float* z0 = ZZ + (size_t)s0 * 576 + lane;
        acc += fmaf(a0.x, z0[0], fmaf(a0.y, z0[64],
                    fmaf(a0.z, z0[128], fmaf(a0.w, z0[192], z0[256]))));
    }
    float v = acc + ZZ[(size_t)n * 576 + 320 + lane] + conv_b[lane];
    m[(size_t)n * 64 + lane] = fmaxf(v, 0.0f);
}

__global__ __launch_bounds__(256) void gru2(const float* __restrict__ m,
                                            const float* __restrict__ ZZ,
                                            const float* __restrict__ w_ih,
                                            const float* __restrict__ b_ih,
                                            const float* __restrict__ b_hh,
                                            float* __restrict__ h,
                                            float* __restrict__ out_final, int N) {
    __shared__ float m_lds[64 * AP];
    __shared__ float w_lds[64 * WP];
    const int n0 = blockIdx.x * 64;
    const int tid = threadIdx.x;
    for (int idx = tid; idx < 4096; idx += 256) {
        int r = idx >> 6, j = idx & 63;
        int n = n0 + r;
        m_lds[j * AP + r] = (n < N) ? m[(size_t)n * 64 + j] : 0.0f;
    }
    const int row_t = tid >> 4, col_t = tid & 15;
    const int r0 = row_t * 4, c0 = col_t * 4;
    float acc[3][4][4] = {};
#pragma unroll
    for (int cb = 0; cb < 3; ++cb) {
        __syncthreads();
        for (int idx = tid; idx < 4096; idx += 256) {
            int c = idx >> 6, j = idx & 63;
            w_lds[j * WP + c] = w_ih[(cb * 64 + c) * 64 + j];
        }
        __syncthreads();
#pragma unroll 4
        for (int j = 0; j < 64; ++j) {
            float av[4];
#pragma unroll
            for (int rr = 0; rr < 4; ++rr) av[rr] = m_lds[j * AP + r0 + rr];
            const float4 w4 = *(const float4*)(w_lds + j * WP + c0);
            const float wv[4] = {w4.x, w4.y, w4.z, w4.w};
#pragma unroll
            for (int rr = 0; rr < 4; ++rr)
#pragma unroll
                for (int cc = 0; cc < 4; ++cc)
                    acc[cb][rr][cc] = fmaf(av[rr], wv[cc], acc[cb][rr][cc]);
        }
    }
#pragma unroll
    for (int rr = 0; rr < 4; ++rr) {
        int n = n0 + r0 + rr;
        if (n >= N) continue;
        const float4 ghr4 = *(const float4*)(ZZ + (size_t)n * 576 + 384 + c0);
        const float4 ghz4 = *(const float4*)(ZZ + (size_t)n * 576 + 448 + c0);
        const float4 ghn4 = *(const float4*)(ZZ + (size_t)n * 576 + 512 + c0);
        const float4 hv4 = *(const float4*)(h + (size_t)n * 64 + c0);
        const float ghr[4] = {ghr4.x, ghr4.y, ghr4.z, ghr4.w};
        const float ghz[4] = {ghz4.x, ghz4.y, ghz4.z, ghz4.w};
        const float ghn[4] = {ghn4.x, ghn4.y, ghn4.z, ghn4.w};
        const float hv[4] = {hv4.x, hv4.y, hv4.z, hv4.w};
        float hnew[4];
#pragma unroll
        for (int cc = 0; cc < 4; ++cc) {
            int l = c0 + cc;
            float rg = sigmoidf_(acc[0][rr][cc] + b_ih[l] + ghr[cc] + b_hh[l]);
            float zg = sigmoidf_(acc[1][rr][cc] + b_ih[64 + l] + ghz[cc] + b_hh[64 + l]);
            float hn = ghn[cc] + b_hh[128 + l];
            float ng = tanhf_(acc[2][rr][cc] + b_ih[128 + l] + rg * hn);
            hnew[cc] = (1.0f - zg) * ng + zg * hv[cc];
        }
        float4 o = make_float4(hnew[0], hnew[1], hnew[2], hnew[3]);
        *(float4*)(h + (size_t)n * 64 + c0) = o;
        if (out_final) *(float4*)(out_final + (size_t)n * 64 + c0) = o;
    }
}

extern "C" void kernel_launch(void* const* d_in, const int* in_sizes, int n_in,
                              void* d_out, int out_size, void* d_ws, size_t ws_size,
                              hipStream_t stream) {
    const float* x      = (const float*)d_in[0];
    const int*   ei     = (const int*)d_in[1];
    const float* ea     = (const float*)d_in[2];
    const float* lin0_w = (const float*)d_in[3];
    const float* lin0_b = (const float*)d_in[4];
    const float* nn_w   = (const float*)d_in[5];
    const float* nn_b   = (const float*)d_in[6];
    const float* root_w = (const float*)d_in[7];
    const float* conv_b = (const float*)d_in[8];
    const float* gw_ih  = (const float*)d_in[9];
    const float* gw_hh  = (const float*)d_in[10];
    const float* gb_ih  = (const float*)d_in[11];
    const float* gb_hh  = (const float*)d_in[12];

    const int N = in_sizes[0] / 32;
    const int E = in_sizes[1] / 2;
    const int RB = (N + 63) / 64;

    float* eattr = (float*)d_ws;                 // [E,4]
    float* ZZ    = eattr + (size_t)E * 4;        // [N,576]
    float* h     = ZZ + (size_t)N * 576;         // [N,64]
    float* m     = h + (size_t)N * 64;           // [N,64]
    int* rowptr  = (int*)(m + (size_t)N * 64);   // [N+1]
    int* cursor  = rowptr + (N + 1);             // [N]
    int* esrc    = cursor + N;                   // [E]
    int* dcnt    = esrc + E;                     // [N]
    int* bsum    = dcnt + N;                     // [2048]
    int* boff    = bsum + 2048;                  // [2048]

    // grid sizing: all-co-resident cooperative grid (phases are grid-stride)
    int perCU = 0;
    (void)hipOccupancyMaxActiveBlocksPerMultiprocessor(&perCU, fused, 256, 0);
    int dev = 0;
    (void)hipGetDevice(&dev);
    int cus = 0;
    (void)hipDeviceGetAttribute(&cus, hipDeviceAttributeMultiprocessorCount, dev);
    if (cus <= 0) cus = 256;
    long grid = (long)perCU * cus;
    if (grid > 1024) grid = 1024;

    hipError_t err = hipErrorUnknown;
    if (grid >= 64) {
        Args p{x, ei, ea, lin0_w, lin0_b, nn_w, nn_b, root_w, conv_b,
               gw_ih, gw_hh, gb_ih, gb_hh,
               ZZ, h, m, eattr, rowptr, cursor, esrc, dcnt, bsum, boff,
               (float*)d_out, N, E, RB};
        void* kp[] = {&p};
        err = hipLaunchCooperativeKernel((const void*)fused, dim3((unsigned)grid),
                                         dim3(256), kp, 0, stream);
    }
    if (err != hipSuccess) {
        // fallback: round-3 multi-kernel path
        zero_k<<<(N + 255) / 256, 256, 0, stream>>>(dcnt, N);
        count_k<<<(E + 255) / 256, 256, 0, stream>>>(ei, dcnt, E);
        lin0_k<<<(N * 64 + 255) / 256, 256, 0, stream>>>(x, lin0_w, lin0_b, h, N);
        scan_k<<<1, 1024, 0, stream>>>(dcnt, rowptr, cursor, N);
        fill_k<<<(E + 255) / 256, 256, 0, stream>>>(ei, (const float4*)ea, cursor, esrc,
                                                    (float4*)eattr, E);
        for (int it = 0; it < 3; ++it) {
            gemm_a3<<<dim3(RB, 3), 256, 0, stream>>>(h, nn_w, nn_b, root_w, gw_hh, ZZ, N);
            agg_k<<<(N + 3) / 4, 256, 0, stream>>>(rowptr, esrc, (const float4*)eattr, ZZ,
                                                   conv_b, m, N);
            gru2<<<RB, 256, 0, stream>>>(m, ZZ, gw_ih, gb_ih, gb_hh, h,
                                         (it == 2) ? (float*)d_out : nullptr, N);
        }
    }
}

// Round 5
// 275.825 us; speedup vs baseline: 4.2861x; 4.2861x over previous
//
#include <hip/hip_runtime.h>
#include <hip/hip_bf16.h>

// N=10000, E=50000, IN=32, H=64 (derived from in_sizes at launch).
//
// theta[e] = sum_k ea[e,k]*W_k + B  =>  msg[e] = sum_k ea[e,k]*(h@W_k)[src] + (h@B)[src]
// Per iter:
//   kA: ZZ[N,576] = h @ [W0|W1|W2|W3|B|root_w|w_hh^T]    (tiled GEMM)
//   kB: per node: CSR gather-agg -> m = relu(agg+root+conv_b) -> gi = m@w_ih^T
//       (LDS-staged w_ih, per-wave broadcast) -> GRU elementwise -> h
// Lesson from round 4: grid.sync() costs ~70-100us on 8-XCD MI355X (L2 writeback);
// kernel boundaries are the CHEAP global barrier (~8us). No cooperative launch.

#define AP 65   // (65j+r)%32 == (j+r)%32 -> conflict-free transposed staging writes
#define WP 68   // float4-aligned rows for w tiles
#define WT 193  // odd stride for transposed w_ih in kB: banks (j+l)%32, conflict-free

__device__ __forceinline__ float sigmoidf_(float x) { return 1.0f / (1.0f + __expf(-x)); }
__device__ __forceinline__ float tanhf_(float x) { return 2.0f / (1.0f + __expf(-2.0f * x)) - 1.0f; }

// ---------------- P0: zero dcnt + lin0 (h = relu(x@lin0_w+b)) -----------------------
__global__ __launch_bounds__(256) void zlin0_k(const float* __restrict__ x,
                                               const float* __restrict__ w,
                                               const float* __restrict__ b,
                                               float* __restrict__ h,
                                               int* __restrict__ dcnt, int N) {
    int gid = blockIdx.x * 256 + threadIdx.x;
    int gsz = gridDim.x * 256;
    for (int i = gid; i < N; i += gsz) dcnt[i] = 0;
    for (int idx = gid; idx < N * 64; idx += gsz) {
        int n = idx >> 6, l = idx & 63;
        float acc = b[l];
#pragma unroll
        for (int j = 0; j < 32; ++j) acc = fmaf(x[n * 32 + j], w[j * 64 + l], acc);
        h[idx] = fmaxf(acc, 0.0f);
    }
}

// ---------------- CSR build ---------------------------------------------------------
__global__ __launch_bounds__(256) void count_k(const int* __restrict__ ei,
                                               int* __restrict__ dcnt, int E) {
    int e = blockIdx.x * 256 + threadIdx.x;
    if (e < E) atomicAdd(dcnt + ei[E + e], 1);
}

__global__ __launch_bounds__(1024) void scan_k(const int* __restrict__ dcnt,
                                               int* __restrict__ rowptr,
                                               int* __restrict__ cursor, int N) {
    __shared__ int part[1024];
    const int t = threadIdx.x;
    const int per = (N + 1023) >> 10;
    const int s0 = t * per;
    const int e0 = min(s0 + per, N);
    int sum = 0;
    for (int i = s0; i < e0; ++i) sum += dcnt[i];
    part[t] = sum;
    __syncthreads();
    for (int d = 1; d < 1024; d <<= 1) {
        int u = (t >= d) ? part[t - d] : 0;
        __syncthreads();
        part[t] += u;
        __syncthreads();
    }
    int off = part[t] - sum;
    for (int i = s0; i < e0; ++i) {
        rowptr[i] = off;
        cursor[i] = off;
        off += dcnt[i];
    }
    if (e0 == N && s0 < N) rowptr[N] = off;
}

__global__ __launch_bounds__(256) void fill_k(const int* __restrict__ ei,
                                              const float4* __restrict__ ea,
                                              int* __restrict__ cursor,
                                              int* __restrict__ esrc,
                                              float4* __restrict__ eattr, int E) {
    int e = blockIdx.x * 256 + threadIdx.x;
    if (e >= E) return;
    int d = ei[E + e];
    int pos = atomicAdd(cursor + d, 1);
    esrc[pos] = ei[e];
    eattr[pos] = ea[e];
}

// ---------------- kA: ZZ[N,576] = h[N,64] @ Wcat[64,576] ----------------------------
// blockIdx.y = g in {0,1,2}: col-blocks cb = 3g + {0,1,2}
//   cb 0..3 -> nn_w k ; cb 4 -> nn_b ; cb 5 -> root_w ; cb 6..8 -> w_hh^T
__global__ __launch_bounds__(256) void gemm_a3(const float* __restrict__ h,
                                               const float* __restrict__ nn_w,
                                               const float* __restrict__ nn_b,
                                               const float* __restrict__ root_w,
                                               const float* __restrict__ w_hh,
                                               float* __restrict__ ZZ, int N) {
    __shared__ float a_lds[64 * AP];
    __shared__ float w_lds[64 * WP];
    const int n0 = blockIdx.x * 64;
    const int g = blockIdx.y;
    const int tid = threadIdx.x;
    for (int idx = tid; idx < 4096; idx += 256) {
        int r = idx >> 6, j = idx & 63;
        int n = n0 + r;
        a_lds[j * AP + r] = (n < N) ? h[n * 64 + j] : 0.0f;
    }
    const int row_t = tid >> 4, col_t = tid & 15;
    const int r0 = row_t * 4, c0 = col_t * 4;
    float acc[3][4][4] = {};
#pragma unroll
    for (int s = 0; s < 3; ++s) {
        int cb = g * 3 + s;
        __syncthreads();
        if (cb < 4) {
            for (int idx = tid; idx < 4096; idx += 256) {
                int j = idx >> 6, c = idx & 63;
                w_lds[j * WP + c] = nn_w[cb * 4096 + j * 64 + c];
            }
        } else if (cb == 4) {
            for (int idx = tid; idx < 4096; idx += 256) {
                int j = idx >> 6, c = idx & 63;
                w_lds[j * WP + c] = nn_b[j * 64 + c];
            }
        } else if (cb == 5) {
            for (int idx = tid; idx < 4096; idx += 256) {
                int j = idx >> 6, c = idx & 63;
                w_lds[j * WP + c] = root_w[j * 64 + c];
            }
        } else {
            int g0 = (cb - 6) * 64;
            for (int idx = tid; idx < 4096; idx += 256) {
                int c = idx >> 6, j = idx & 63;
                w_lds[j * WP + c] = w_hh[(g0 + c) * 64 + j];
            }
        }
        __syncthreads();
#pragma unroll 4
        for (int j = 0; j < 64; ++j) {
            float av[4];
#pragma unroll
            for (int rr = 0; rr < 4; ++rr) av[rr] = a_lds[j * AP + r0 + rr];
            const float4 w4 = *(const float4*)(w_lds + j * WP + c0);
            const float wv[4] = {w4.x, w4.y, w4.z, w4.w};
#pragma unroll
            for (int rr = 0; rr < 4; ++rr)
#pragma unroll
                for (int cc = 0; cc < 4; ++cc)
                    acc[s][rr][cc] = fmaf(av[rr], wv[cc], acc[s][rr][cc]);
        }
    }
#pragma unroll
    for (int s = 0; s < 3; ++s) {
        const int cbase = (g * 3 + s) * 64 + c0;
#pragma unroll
        for (int rr = 0; rr < 4; ++rr) {
            int n = n0 + r0 + rr;
            if (n < N)
                *(float4*)(ZZ + (size_t)n * 576 + cbase) =
                    make_float4(acc[s][rr][0], acc[s][rr][1], acc[s][rr][2], acc[s][rr][3]);
        }
    }
}

// ---------------- kB: CSR agg -> m -> gi = m@w_ih^T -> GRU -> h ---------------------
// One wave per node (grid-stride). w_ih staged transposed in LDS once per block:
//   w_t[j*WT + gl] = w_ih[gl*64 + j]  (gl = gate*64+l). Odd WT -> conflict-free.
// Per node: lane l owns column l. m broadcast via per-wave LDS row.
__global__ __launch_bounds__(256) void aggru_k(const int* __restrict__ rowptr,
                                               const int* __restrict__ esrc,
                                               const float4* __restrict__ eattr,
                                               const float* __restrict__ ZZ,
                                               const float* __restrict__ conv_b,
                                               const float* __restrict__ w_ih,
                                               const float* __restrict__ b_ih,
                                               const float* __restrict__ b_hh,
                                               float* __restrict__ h,
                                               float* __restrict__ out_final,
                                               int N, int nwaves) {
    __shared__ float w_t[64 * WT];
    __shared__ float m_buf[4 * 64];
    const int tid = threadIdx.x;
    for (int idx = tid; idx < 12288; idx += 256) {
        int j = idx & 63, gl = idx >> 6;
        w_t[j * WT + gl] = w_ih[idx];  // w_ih[gl*64+j] == w_ih[idx]
    }
    __syncthreads();

    const int lane = tid & 63;
    const int wv = tid >> 6;
    float* mrow = m_buf + wv * 64;

    // lane-invariant-per-column biases, hoisted out of the node loop
    const float cb   = conv_b[lane];
    const float bir  = b_ih[lane], biz = b_ih[64 + lane], bin_ = b_ih[128 + lane];
    const float bhr  = b_hh[lane], bhz = b_hh[64 + lane], bhn  = b_hh[128 + lane];

    int gw = (blockIdx.x * 256 + tid) >> 6;
    for (int n = gw; n < N; n += nwaves) {
        const int b = rowptr[n], e = rowptr[n + 1];
        float acc = 0.0f;
        int i = b;
        for (; i + 2 <= e; i += 2) {
            int s0 = esrc[i], s1 = esrc[i + 1];
            float4 a0 = eattr[i], a1 = eattr[i + 1];
            const float* z0 = ZZ + (size_t)s0 * 576 + lane;
            const float* z1 = ZZ + (size_t)s1 * 576 + lane;
            float p0 = z0[0], p1 = z0[64], p2 = z0[128], p3 = z0[192], p4 = z0[256];
            float q0 = z1[0], q1 = z1[64], q2 = z1[128], q3 = z1[192], q4 = z1[256];
            acc += fmaf(a0.x, p0, fmaf(a0.y, p1, fmaf(a0.z, p2, fmaf(a0.w, p3, p4))));
            acc += fmaf(a1.x, q0, fmaf(a1.y, q1, fmaf(a1.z, q2, fmaf(a1.w, q3, q4))));
        }
        if (i < e) {
            int s0 = esrc[i];
            float4 a0 = eattr[i];
            const float* z0 = ZZ + (size_t)s0 * 576 + lane;
            acc += fmaf(a0.x, z0[0], fmaf(a0.y, z0[64],
                        fmaf(a0.z, z0[128], fmaf(a0.w, z0[192], z0[256]))));
        }
        const float* zn = ZZ + (size_t)n * 576;
        float m = fmaxf(acc + zn[320 + lane] + cb, 0.0f);
        mrow[lane] = m;  // same-wave LDS: visible after lgkmcnt, no barrier needed

        float gr = 0.0f, gz = 0.0f, gn = 0.0f;
#pragma unroll 4
        for (int j = 0; j < 64; ++j) {
            float mj = mrow[j];  // uniform address -> LDS broadcast
            gr = fmaf(mj, w_t[j * WT + lane], gr);
            gz = fmaf(mj, w_t[j * WT + 64 + lane], gz);
            gn = fmaf(mj, w_t[j * WT + 128 + lane], gn);
        }
        float ghr = zn[384 + lane], ghz = zn[448 + lane], ghn = zn[512 + lane];
        float hv = h[(size_t)n * 64 + lane];
        float r = sigmoidf_(gr + bir + ghr + bhr);
        float z = sigmoidf_(gz + biz + ghz + bhz);
        float ng = tanhf_(gn + bin_ + r * (ghn + bhn));
        float hnew = (1.0f - z) * ng + z * hv;
        h[(size_t)n * 64 + lane] = hnew;
        if (out_final) out_final[(size_t)n * 64 + lane] = hnew;
    }
}

extern "C" void kernel_launch(void* const* d_in, const int* in_sizes, int n_in,
                              void* d_out, int out_size, void* d_ws, size_t ws_size,
                              hipStream_t stream) {
    const float* x      = (const float*)d_in[0];
    const int*   ei     = (const int*)d_in[1];
    const float* ea     = (const float*)d_in[2];
    const float* lin0_w = (const float*)d_in[3];
    const float* lin0_b = (const float*)d_in[4];
    const float* nn_w   = (const float*)d_in[5];
    const float* nn_b   = (const float*)d_in[6];
    const float* root_w = (const float*)d_in[7];
    const float* conv_b = (const float*)d_in[8];
    const float* gw_ih  = (const float*)d_in[9];
    const float* gw_hh  = (const float*)d_in[10];
    const float* gb_ih  = (const float*)d_in[11];
    const float* gb_hh  = (const float*)d_in[12];

    const int N = in_sizes[0] / 32;
    const int E = in_sizes[1] / 2;
    const int RB = (N + 63) / 64;

    float* eattr = (float*)d_ws;                 // [E,4]
    float* ZZ    = eattr + (size_t)E * 4;        // [N,576]
    float* h     = ZZ + (size_t)N * 576;         // [N,64]
    int* rowptr  = (int*)(h + (size_t)N * 64);   // [N+1]
    int* cursor  = rowptr + (N + 1);             // [N]
    int* esrc    = cursor + N;                   // [E]
    int* dcnt    = esrc + E;                     // [N]

    // prologue: 4 dispatches
    zlin0_k<<<(N * 64 + 255) / 256, 256, 0, stream>>>(x, lin0_w, lin0_b, h, dcnt, N);
    count_k<<<(E + 255) / 256, 256, 0, stream>>>(ei, dcnt, E);
    scan_k<<<1, 1024, 0, stream>>>(dcnt, rowptr, cursor, N);
    fill_k<<<(E + 255) / 256, 256, 0, stream>>>(ei, (const float4*)ea, cursor, esrc,
                                                (float4*)eattr, E);

    // kB grid: 3 blocks/CU resident (50.4KB LDS), 640 blocks -> 2560 waves
    const int kb_blocks = 640;
    const int nwaves = kb_blocks * 4;

    for (int it = 0; it < 3; ++it) {
        gemm_a3<<<dim3(RB, 3), 256, 0, stream>>>(h, nn_w, nn_b, root_w, gw_hh, ZZ, N);
        aggru_k<<<kb_blocks, 256, 0, stream>>>(rowptr, esrc, (const float4*)eattr, ZZ,
                                               conv_b, gw_ih, gb_ih, gb_hh, h,
                                               (it == 2) ? (float*)d_out : nullptr,
                                               N, nwaves);
    }
}